// Round 12
// baseline (57.276 us; speedup 1.0000x reference)
//
#include <hip/hip_runtime.h>
#include <hip/hip_bf16.h>

// Fully fused MLP: 32 -> 64 -> (4x) 64 -> 3, relu hidden, sigmoid out.
// Round-12: r11 refuted the register-pressure theory (small version NaN'd too).
// Layout algebra re-verified (kpos relabel, bias rows, x K-tiling) and layout
// errors can't create NaN from finite data anyway. Remaining suspects unique
// to r10/r11: (1) union-punning f32x16 ldbias, (2) inline-asm cvtpk fed raw
// f32x16 acc elements (r7-proven form interposes fmaxf). This round removes
// BOTH, keeping all 32x32 math identical:
//  - ldbias: direct aligned f32x16 LDS load (simg aligned(64), offsets 64B-mult)
//  - fragof: fmaxf-then-cvtpk (r7-proven relu form, no pkrelu)
// If this still NaNs, the 32x32/f32x16 path is condemned; revert to r9.
//
// Weight frags (1KB each): 0..3 W_in[nt][K] | 4..35 W_hid[L][nt][K] | 36..39 W_out[K]
// Bias floats at BIAS_F32: [0..63] in[nt][hi][16] | [64..319] hid[L][nt][hi][16]
//                          | [320..351] out[hi][16]

typedef __attribute__((ext_vector_type(8))) short bf16x8;
typedef __attribute__((ext_vector_type(4))) float f32x4;
typedef __attribute__((ext_vector_type(16))) float f32x16;

#define NWFRAG 40
#define BIAS_F32 10240               // float offset of bias region (= 40*1024/4)
#define IMG_BYTES 42368              // 40960 weight bytes + 352*4 bias bytes
#define IMG_U4 2648

struct F3 { float a, b, c; };        // 12B packed output store

// packed f32x2 -> bf16x2, RNE, 1 instruction.
__device__ __forceinline__ unsigned cvtpk(float lo, float hi) {
    unsigned r;
    asm("v_cvt_pk_bf16_f32 %0, %1, %2" : "=v"(r) : "v"(lo), "v"(hi));
    return r;
}

// inverse neuron relabeling: k-slot s -> original neuron index
// n = 32s5 + 16s4 + 8s2 + 4s3 + 2s1 + s0
__device__ __forceinline__ int pinv32(int s) {
    return ((s >> 5) & 1) * 32 + ((s >> 4) & 1) * 16 + ((s >> 2) & 1) * 8 +
           ((s >> 3) & 1) * 4 + ((s >> 1) & 1) * 2 + (s & 1);
}

// weight frag value (frag F < 40, lane). A-frag 32x32x16: row=lane&31, k=8*(lane>>5)+e.
__device__ uint4 frag_value_w(int F, int lane,
        const float* __restrict__ W_in, const float* __restrict__ W_hid,
        const float* __restrict__ W_out) {
    const int j = lane & 31, hi = lane >> 5;
    uint4 r = {0u, 0u, 0u, 0u};
    if (F < 4) {                                  // W_in: F = nt*2 + K, natural k
        int nt = F >> 1, K = F & 1;
        const float* row = W_in + (nt * 32 + j) * 32 + K * 16 + hi * 8;
        r.x = cvtpk(row[0], row[1]); r.y = cvtpk(row[2], row[3]);
        r.z = cvtpk(row[4], row[5]); r.w = cvtpk(row[6], row[7]);
    } else if (F < 36) {                          // W_hid: F-4 = L*8 + nt*4 + K, pinv32 k
        int q = F - 4, L = q >> 3, nt = (q >> 2) & 1, K = q & 3;
        const float* row = W_hid + (L * 64 + nt * 32 + j) * 64;
        int s0 = K * 16 + hi * 8;
        r.x = cvtpk(row[pinv32(s0 + 0)], row[pinv32(s0 + 1)]);
        r.y = cvtpk(row[pinv32(s0 + 2)], row[pinv32(s0 + 3)]);
        r.z = cvtpk(row[pinv32(s0 + 4)], row[pinv32(s0 + 5)]);
        r.w = cvtpk(row[pinv32(s0 + 6)], row[pinv32(s0 + 7)]);
    } else {                                      // W_out: K = F-36, rows 3..31 zero
        int K = F - 36;
        if (j < 3) {
            const float* row = W_out + j * 64;
            int s0 = K * 16 + hi * 8;
            r.x = cvtpk(row[pinv32(s0 + 0)], row[pinv32(s0 + 1)]);
            r.y = cvtpk(row[pinv32(s0 + 2)], row[pinv32(s0 + 3)]);
            r.z = cvtpk(row[pinv32(s0 + 4)], row[pinv32(s0 + 5)]);
            r.w = cvtpk(row[pinv32(s0 + 6)], row[pinv32(s0 + 7)]);
        }
    }
    return r;
}

// bias C-frag element: reg rr of lane-half hi maps to row (rr&3)+8*((rr>>2)&3)+4*hi
__device__ __forceinline__ float bias_val(int idx,
        const float* __restrict__ b_in, const float* __restrict__ b_hid,
        const float* __restrict__ b_out) {
    if (idx < 64) {
        int nt = idx >> 5, hi = (idx >> 4) & 1, rr = idx & 15;
        return b_in[nt * 32 + (rr & 3) + 8 * ((rr >> 2) & 3) + 4 * hi];
    }
    if (idx < 320) {
        int q = idx - 64, L = q >> 6, nt = (q >> 5) & 1, hi = (q >> 4) & 1, rr = q & 15;
        return b_hid[L * 64 + nt * 32 + (rr & 3) + 8 * ((rr >> 2) & 3) + 4 * hi];
    }
    int q = idx - 320, hi = q >> 4, rr = q & 15;
    return (hi == 0 && rr < 3) ? b_out[rr] : 0.f;
}

__global__ void prep_kernel(const float* __restrict__ W_in,  const float* __restrict__ b_in,
                            const float* __restrict__ W_hid, const float* __restrict__ b_hid,
                            const float* __restrict__ W_out, const float* __restrict__ b_out,
                            uint4* __restrict__ img) {
    const int F = blockIdx.x, t = threadIdx.x;
    if (F < NWFRAG) {
        img[F * 64 + t] = frag_value_w(F, t, W_in, W_hid, W_out);
    } else {
        float* fb = (float*)img + BIAS_F32;
        for (int idx = t; idx < 352; idx += 64)
            fb[idx] = bias_val(idx, b_in, b_hid, b_out);
    }
}

// relu + frag extraction, r7-proven form: fmaxf each element, then cvtpk.
// (asm inputs are fmaxf results in plain VGPRs, never raw acc extracts.)
template<int C>
__device__ __forceinline__ bf16x8 fragof(f32x16 a) {
    union { bf16x8 v; unsigned u[4]; } t;
    t.u[0] = cvtpk(fmaxf(a[8 * C + 0], 0.f), fmaxf(a[8 * C + 1], 0.f));
    t.u[1] = cvtpk(fmaxf(a[8 * C + 2], 0.f), fmaxf(a[8 * C + 3], 0.f));
    t.u[2] = cvtpk(fmaxf(a[8 * C + 4], 0.f), fmaxf(a[8 * C + 5], 0.f));
    t.u[3] = cvtpk(fmaxf(a[8 * C + 6], 0.f), fmaxf(a[8 * C + 7], 0.f));
    return t.v;
}

// bias C-operand: direct aligned f32x16 load (no union punning).
// All call sites use off % 16 == 0 and the bias base is 64B-aligned.
__device__ __forceinline__ f32x16 ldbias(const float* sb, int off, int hi) {
    return *(const f32x16*)(sb + off + hi * 16);
}

#define MFMA32(a, b, c) __builtin_amdgcn_mfma_f32_32x32x16_bf16((a), (b), (c), 0, 0, 0)

template<bool FAST>
__global__ __launch_bounds__(512, 4) void mlp_kernel(
        const float* __restrict__ x, const uint4* __restrict__ img,
        const float* __restrict__ gW_in,  const float* __restrict__ gb_in,
        const float* __restrict__ gW_hid, const float* __restrict__ gb_hid,
        const float* __restrict__ gW_out, const float* __restrict__ gb_out,
        float* __restrict__ out) {
    __shared__ __attribute__((aligned(64))) uint4 simg[IMG_U4];
    const int tid = threadIdx.x;

    if (FAST) {
#pragma unroll
        for (int i = 0; i < 6; ++i) {
            int idx = tid + i * 512;
            if (idx < IMG_U4) simg[idx] = img[idx];
        }
    } else {
        for (int idx = tid; idx < NWFRAG * 64; idx += 512)
            simg[idx] = frag_value_w(idx >> 6, idx & 63, gW_in, gW_hid, gW_out);
        {
            float* fb = (float*)simg + BIAS_F32;
            for (int idx = tid; idx < 352; idx += 512)
                fb[idx] = bias_val(idx, gb_in, gb_hid, gb_out);
        }
    }

    const int wave = tid >> 6, lane = tid & 63;
    const int j = lane & 31, hi = lane >> 5;
    const int base = (blockIdx.x * 8 + wave) * 256;

    // iter-0 x load issued before the barrier (hides under staging).
    // lane needs x[p][{8hi..8hi+7} U {16+8hi..16+8hi+7}]
    f32x4 raw[4];
    {
        const float* xp = x + (size_t)(base + j) * 32 + hi * 8;
        raw[0] = *(const f32x4*)xp;        raw[1] = *(const f32x4*)(xp + 4);
        raw[2] = *(const f32x4*)(xp + 16); raw[3] = *(const f32x4*)(xp + 20);
    }
    __syncthreads();

    const uint4*  lp = &simg[lane];              // weight frag F at lp[F*64]
    const float*  sb = (const float*)simg + BIAS_F32;

#pragma unroll 1
    for (int it = 0; it < 8; ++it) {
        // pack x into B-frags (raw dies here)
        bf16x8 xf0, xf1;
        {
            union { bf16x8 v; unsigned u[4]; } t0, t1;
            t0.u[0] = cvtpk(raw[0][0], raw[0][1]);
            t0.u[1] = cvtpk(raw[0][2], raw[0][3]);
            t0.u[2] = cvtpk(raw[1][0], raw[1][1]);
            t0.u[3] = cvtpk(raw[1][2], raw[1][3]);
            t1.u[0] = cvtpk(raw[2][0], raw[2][1]);
            t1.u[1] = cvtpk(raw[2][2], raw[2][3]);
            t1.u[2] = cvtpk(raw[3][0], raw[3][1]);
            t1.u[3] = cvtpk(raw[3][2], raw[3][3]);
            xf0 = t0.v; xf1 = t1.v;
        }

        // prefetch next iter's x (in flight across the whole layer stack)
        {
            const int itn = (it < 7) ? it + 1 : it;
            const float* xp = x + (size_t)(base + itn * 32 + j) * 32 + hi * 8;
            raw[0] = *(const f32x4*)xp;        raw[1] = *(const f32x4*)(xp + 4);
            raw[2] = *(const f32x4*)(xp + 16); raw[3] = *(const f32x4*)(xp + 20);
        }

        bf16x8 h0, h1, h2, h3;
        // ======== input layer: 2 ntiles x K-chain of 2 ========
        {
            __builtin_amdgcn_s_setprio(1);
            f32x16 a0 = MFMA32(*(const bf16x8*)&lp[0 * 64], xf0, ldbias(sb, 0, hi));
            a0 = MFMA32(*(const bf16x8*)&lp[1 * 64], xf1, a0);
            f32x16 a1 = MFMA32(*(const bf16x8*)&lp[2 * 64], xf0, ldbias(sb, 32, hi));
            a1 = MFMA32(*(const bf16x8*)&lp[3 * 64], xf1, a1);
            __builtin_amdgcn_s_setprio(0);
            h0 = fragof<0>(a0); h1 = fragof<1>(a0);
            h2 = fragof<0>(a1); h3 = fragof<1>(a1);
        }
        // ======== 4 hidden layers: 2 ntiles x K-chain of 4 ========
#pragma unroll
        for (int L = 0; L < 4; ++L) {
            const int wb = (4 + L * 8);
            const int bb = 64 + L * 64;
            __builtin_amdgcn_s_setprio(1);
            f32x16 a0 = MFMA32(*(const bf16x8*)&lp[(wb + 0) * 64], h0, ldbias(sb, bb, hi));
            a0 = MFMA32(*(const bf16x8*)&lp[(wb + 1) * 64], h1, a0);
            a0 = MFMA32(*(const bf16x8*)&lp[(wb + 2) * 64], h2, a0);
            a0 = MFMA32(*(const bf16x8*)&lp[(wb + 3) * 64], h3, a0);
            f32x16 a1 = MFMA32(*(const bf16x8*)&lp[(wb + 4) * 64], h0, ldbias(sb, bb + 32, hi));
            a1 = MFMA32(*(const bf16x8*)&lp[(wb + 5) * 64], h1, a1);
            a1 = MFMA32(*(const bf16x8*)&lp[(wb + 6) * 64], h2, a1);
            a1 = MFMA32(*(const bf16x8*)&lp[(wb + 7) * 64], h3, a1);
            __builtin_amdgcn_s_setprio(0);
            h0 = fragof<0>(a0); h1 = fragof<1>(a0);
            h2 = fragof<0>(a1); h3 = fragof<1>(a1);
        }
        // ======== output layer: K-chain of 4, rows 0..2 valid ========
        {
            __builtin_amdgcn_s_setprio(1);
            f32x16 zf = MFMA32(*(const bf16x8*)&lp[36 * 64], h0, ldbias(sb, 320, hi));
            zf = MFMA32(*(const bf16x8*)&lp[37 * 64], h1, zf);
            zf = MFMA32(*(const bf16x8*)&lp[38 * 64], h2, zf);
            zf = MFMA32(*(const bf16x8*)&lp[39 * 64], h3, zf);
            __builtin_amdgcn_s_setprio(0);
            // D: col=lane&31=point, row=(r&3)+8*(r>>2)+4*hi -> rows 0..2 = regs 0..2 @ hi==0
            if (hi == 0) {
                const int p = base + it * 32 + j;
                F3 v;
                v.a = __builtin_amdgcn_rcpf(1.f + __expf(-zf[0]));
                v.b = __builtin_amdgcn_rcpf(1.f + __expf(-zf[1]));
                v.c = __builtin_amdgcn_rcpf(1.f + __expf(-zf[2]));
                *(F3*)(out + (size_t)p * 3) = v;
            }
        }
    }
}

extern "C" void kernel_launch(void* const* d_in, const int* in_sizes, int n_in,
                              void* d_out, int out_size, void* d_ws, size_t ws_size,
                              hipStream_t stream) {
    const float* x     = (const float*)d_in[0];
    const float* W_in  = (const float*)d_in[1];
    const float* b_in  = (const float*)d_in[2];
    const float* W_hid = (const float*)d_in[3];
    const float* b_hid = (const float*)d_in[4];
    const float* W_out = (const float*)d_in[5];
    const float* b_out = (const float*)d_in[6];
    float* out = (float*)d_out;

    int n = in_sizes[0] / 32;              // 1<<20 points
    int nblocks = n / 2048;                // 8 waves * 256 points per block = 512 blocks

    if (ws_size >= (size_t)IMG_BYTES) {
        hipLaunchKernelGGL(prep_kernel, dim3(NWFRAG + 1), dim3(64), 0, stream,
                           W_in, b_in, W_hid, b_hid, W_out, b_out, (uint4*)d_ws);
        hipLaunchKernelGGL((mlp_kernel<true>), dim3(nblocks), dim3(512), 0, stream,
                           x, (const uint4*)d_ws,
                           W_in, b_in, W_hid, b_hid, W_out, b_out, out);
    } else {
        hipLaunchKernelGGL((mlp_kernel<false>), dim3(nblocks), dim3(512), 0, stream,
                           x, (const uint4*)d_ws,
                           W_in, b_in, W_hid, b_hid, W_out, b_out, out);
    }
}

// Round 13
// 46.198 us; speedup vs baseline: 1.2398x; 1.2398x over previous
//
#include <hip/hip_runtime.h>
#include <hip/hip_bf16.h>

// Fully fused MLP: 32 -> 64 -> (4x) 64 -> 3, relu hidden, sigmoid out.
// bf16 MFMA (16x16x32), fp32 accum, operand-swapped (D[neuron][point] = W*H).
// Point index is lane-invariant across layers; neuron relabeling pi baked into
// next-layer weight columns at prep time -> lane-local layer handoff.
//
// Round-13: r10-r12 proved the 32x32x16 path is a perf dead end (57.3us vs
// r9's 46.1: 2 chains of 4 dependent MFMAs collapse ILP; fixing it costs
// spill or VALU). The NaN was the f32x16 union punning (r12 bisect).
// TLP is hard-capped at 4 waves/SIMD (waves halve at VGPR>64, acc alone needs
// 32-64). The only lever that ever moved this kernel is arbitration (setprio,
// +18% in r9). This round: r9 byte-identical except s_setprio(1) -> (3).
//
// Frag map (weights): 0..3 W_in[nt] | 4..35 W_hid[L][nt][f] | 36..37 W_out[f]
// Bias floats at BIAS_F32: [0..63] b_in | [64..319] b_hid | [320..335] b_out+pad

typedef __attribute__((ext_vector_type(8))) short bf16x8;
typedef __attribute__((ext_vector_type(4))) float f32x4;

#define NWFRAG 38
#define BIAS_F32 9728                 // float offset of bias region (= 38*1024/4)
#define IMG_BYTES 40256               // 38912 weight bytes + 336*4 bias bytes
#define IMG_U4 2516

struct F3 { float a, b, c; };         // 12B packed output store

// packed f32x2 -> bf16x2, RNE, 1 instruction. lo = low 16 bits.
__device__ __forceinline__ unsigned cvtpk(float lo, float hi) {
    unsigned r;
    asm("v_cvt_pk_bf16_f32 %0, %1, %2" : "=v"(r) : "v"(lo), "v"(hi));
    return r;
}

// packed bf16x2 relu: int16 max vs register-zero (bit-exact, r9-proven).
__device__ __forceinline__ unsigned pkrelu(unsigned u, unsigned z) {
    unsigned r;
    asm("v_pk_max_i16 %0, %1, %2" : "=v"(r) : "v"(u), "v"(z));
    return r;
}

// inverse of the neuron relabeling pi: k-slot s -> actual neuron index
__device__ __forceinline__ int pinv(int s) {
    return ((s >> 5) & 1) * 32 + ((s >> 2) & 1) * 16 + ((s >> 3) & 3) * 4 + (s & 3);
}

// weight frag value (frag F < 38, lane)
__device__ uint4 frag_value_w(int F, int lane,
        const float* __restrict__ W_in, const float* __restrict__ W_hid,
        const float* __restrict__ W_out) {
    const int j = lane & 15, g = lane >> 4;
    uint4 r = {0u, 0u, 0u, 0u};
    if (F < 4) {                                   // W_in A-frag, natural k
        const float* row = W_in + (F * 16 + j) * 32 + 8 * g;
        r.x = cvtpk(row[0], row[1]); r.y = cvtpk(row[2], row[3]);
        r.z = cvtpk(row[4], row[5]); r.w = cvtpk(row[6], row[7]);
    } else if (F < 36) {                           // W_hid A-frag, pi-relabeled k
        int q = F - 4, L = q >> 3, nt = (q >> 1) & 3, f = q & 1;
        const float* row = W_hid + (L * 64 + nt * 16 + j) * 64;
        int s0 = 32 * f + 8 * g;
        r.x = cvtpk(row[pinv(s0 + 0)], row[pinv(s0 + 1)]);
        r.y = cvtpk(row[pinv(s0 + 2)], row[pinv(s0 + 3)]);
        r.z = cvtpk(row[pinv(s0 + 4)], row[pinv(s0 + 5)]);
        r.w = cvtpk(row[pinv(s0 + 6)], row[pinv(s0 + 7)]);
    } else {                                       // W_out A-frag (rows 3..15 zero)
        int f = F - 36;
        if (j < 3) {
            const float* row = W_out + j * 64;
            int s0 = 32 * f + 8 * g;
            r.x = cvtpk(row[pinv(s0 + 0)], row[pinv(s0 + 1)]);
            r.y = cvtpk(row[pinv(s0 + 2)], row[pinv(s0 + 3)]);
            r.z = cvtpk(row[pinv(s0 + 4)], row[pinv(s0 + 5)]);
            r.w = cvtpk(row[pinv(s0 + 6)], row[pinv(s0 + 7)]);
        }
    }
    return r;
}

__device__ __forceinline__ float bias_val(int idx,
        const float* __restrict__ b_in, const float* __restrict__ b_hid,
        const float* __restrict__ b_out) {
    if (idx < 64)  return b_in[idx];
    if (idx < 320) return b_hid[idx - 64];
    return (idx - 320 < 3) ? b_out[idx - 320] : 0.f;
}

__global__ void prep_kernel(const float* __restrict__ W_in,  const float* __restrict__ b_in,
                            const float* __restrict__ W_hid, const float* __restrict__ b_hid,
                            const float* __restrict__ W_out, const float* __restrict__ b_out,
                            uint4* __restrict__ img) {
    const int F = blockIdx.x, t = threadIdx.x;
    if (F < NWFRAG) {
        img[F * 64 + t] = frag_value_w(F, t, W_in, W_hid, W_out);
    } else {
        float* fb = (float*)img + BIAS_F32;
        for (int idx = t; idx < 336; idx += 64)
            fb[idx] = bias_val(idx, b_in, b_hid, b_out);
    }
}

// relu + lane-local pi-pack: acc[4] (f32x4) -> h[2] (bf16x8)
// cvtpk first, then packed int16 relu (bit-exact vs fmaxf-then-cvtpk).
__device__ __forceinline__ void relu_pack(const f32x4 a[4], bf16x8 h[2], unsigned z) {
#pragma unroll
    for (int f = 0; f < 2; ++f) {
        union { bf16x8 v; unsigned u[4]; } t;
        t.u[0] = pkrelu(cvtpk(a[2 * f][0], a[2 * f][1]), z);
        t.u[1] = pkrelu(cvtpk(a[2 * f][2], a[2 * f][3]), z);
        t.u[2] = pkrelu(cvtpk(a[2 * f + 1][0], a[2 * f + 1][1]), z);
        t.u[3] = pkrelu(cvtpk(a[2 * f + 1][2], a[2 * f + 1][3]), z);
        h[f] = t.v;
    }
}

#define MFMA(a, b, c) __builtin_amdgcn_mfma_f32_16x16x32_bf16((a), (b), (c), 0, 0, 0)

template<bool FAST>
__global__ __launch_bounds__(512, 4) void mlp_kernel(
        const float* __restrict__ x, const uint4* __restrict__ img,
        const float* __restrict__ gW_in,  const float* __restrict__ gb_in,
        const float* __restrict__ gW_hid, const float* __restrict__ gb_hid,
        const float* __restrict__ gW_out, const float* __restrict__ gb_out,
        float* __restrict__ out) {
    __shared__ uint4 simg[IMG_U4];
    const int tid = threadIdx.x;

    if (FAST) {
#pragma unroll
        for (int i = 0; i < 5; ++i) {
            int idx = tid + i * 512;
            if (idx < IMG_U4) simg[idx] = img[idx];
        }
    } else {
        for (int idx = tid; idx < NWFRAG * 64; idx += 512)
            simg[idx] = frag_value_w(idx >> 6, idx & 63, gW_in, gW_hid, gW_out);
        {
            float* fb = (float*)simg + BIAS_F32;
            for (int idx = tid; idx < 336; idx += 512)
                fb[idx] = bias_val(idx, gb_in, gb_hid, gb_out);
        }
    }

    const int wave = tid >> 6, lane = tid & 63;
    const int j = lane & 15, g = lane >> 4;
    const int base = (blockIdx.x * 8 + wave) * 256;

    // iter-0 x load issued before the barrier (hides under staging)
    f32x4 raw[4][2];
    {
        const float* xp = x + (size_t)(base + j) * 32 + 8 * g;
#pragma unroll
        for (int t = 0; t < 4; ++t) {
            raw[t][0] = *(const f32x4*)(xp + t * 512);
            raw[t][1] = *(const f32x4*)(xp + t * 512 + 4);
        }
    }
    __syncthreads();

    const uint4*  lp = &simg[lane];              // weight frag F at lp[F*64]
    const float*  sb = (const float*)simg + BIAS_F32;
    const unsigned z = 0;                        // register zero for pkrelu

#pragma unroll 1
    for (int it = 0; it < 4; ++it) {
        const int p0 = base + it * 64;

        // pack current x into B-frags (raw regs die here)
        bf16x8 xf[4];
#pragma unroll
        for (int t = 0; t < 4; ++t) {
            union { bf16x8 v; unsigned u[4]; } a;
            a.u[0] = cvtpk(raw[t][0][0], raw[t][0][1]);
            a.u[1] = cvtpk(raw[t][0][2], raw[t][0][3]);
            a.u[2] = cvtpk(raw[t][1][0], raw[t][1][1]);
            a.u[3] = cvtpk(raw[t][1][2], raw[t][1][3]);
            xf[t] = a.v;
        }

        // ======== input layer: all 4 tiles ========
        bf16x8 hfrag[4][2];
        {
            f32x4 acc[4][4];
            __builtin_amdgcn_s_setprio(3);
#pragma unroll
            for (int nt = 0; nt < 4; ++nt) {
                bf16x8 w  = *(const bf16x8*)&lp[nt * 64];
                f32x4  bz = *(const f32x4*)&sb[nt * 16 + 4 * g];
#pragma unroll
                for (int t = 0; t < 4; ++t)
                    acc[t][nt] = MFMA(w, xf[t], bz);
            }
            __builtin_amdgcn_s_setprio(0);
#pragma unroll
            for (int t = 0; t < 4; ++t) relu_pack(acc[t], hfrag[t], z);
        }

        // ======== 4 hidden layers: weights read once, tiles pair-staged ========
#pragma unroll
        for (int L = 0; L < 4; ++L) {
            const int wb = (4 + L * 8) * 64;
            bf16x8 w0[4], w1[4]; f32x4 bz[4];
#pragma unroll
            for (int nt = 0; nt < 4; ++nt) {
                w0[nt] = *(const bf16x8*)&lp[wb + (2 * nt) * 64];
                w1[nt] = *(const bf16x8*)&lp[wb + (2 * nt + 1) * 64];
                bz[nt] = *(const f32x4*)&sb[64 + L * 64 + nt * 16 + 4 * g];
            }
#pragma unroll
            for (int pr = 0; pr < 2; ++pr) {
                f32x4 pa[2][4];
                __builtin_amdgcn_s_setprio(3);
#pragma unroll
                for (int q = 0; q < 2; ++q)
#pragma unroll
                    for (int nt = 0; nt < 4; ++nt)
                        pa[q][nt] = MFMA(w0[nt], hfrag[2 * pr + q][0], bz[nt]);
#pragma unroll
                for (int q = 0; q < 2; ++q)
#pragma unroll
                    for (int nt = 0; nt < 4; ++nt)
                        pa[q][nt] = MFMA(w1[nt], hfrag[2 * pr + q][1], pa[q][nt]);
                __builtin_amdgcn_s_setprio(0);
#pragma unroll
                for (int q = 0; q < 2; ++q) relu_pack(pa[q], hfrag[2 * pr + q], z);
            }
        }

        // ======== output layer ========
        bf16x8 wo0 = *(const bf16x8*)&lp[36 * 64];
        bf16x8 wo1 = *(const bf16x8*)&lp[37 * 64];
        f32x4  bo  = *(const f32x4*)&sb[320 + 4 * g];   // g>0 rows read zero pad
        f32x4 zacc[4];
        __builtin_amdgcn_s_setprio(3);
#pragma unroll
        for (int t = 0; t < 4; ++t) {
            f32x4 tmp = MFMA(wo0, hfrag[t][0], bo);
            zacc[t] = MFMA(wo1, hfrag[t][1], tmp);
        }
        __builtin_amdgcn_s_setprio(0);

        // prefetch next iter's x (raw regs were dead since pack)
        {
            const int pn = (it < 3) ? p0 + 64 : p0;
            const float* xp = x + (size_t)(pn + j) * 32 + 8 * g;
#pragma unroll
            for (int t = 0; t < 4; ++t) {
                raw[t][0] = *(const f32x4*)(xp + t * 512);
                raw[t][1] = *(const f32x4*)(xp + t * 512 + 4);
            }
        }

        // sigmoid + packed 12B stores (rows 0..2 live in g==0)
        if (g == 0) {
            float* ob = out + (size_t)(p0 + j) * 3;
#pragma unroll
            for (int t = 0; t < 4; ++t) {
                F3 v;
                v.a = __builtin_amdgcn_rcpf(1.f + __expf(-zacc[t][0]));
                v.b = __builtin_amdgcn_rcpf(1.f + __expf(-zacc[t][1]));
                v.c = __builtin_amdgcn_rcpf(1.f + __expf(-zacc[t][2]));
                *(F3*)(ob + t * 48) = v;
            }
        }
    }
}

extern "C" void kernel_launch(void* const* d_in, const int* in_sizes, int n_in,
                              void* d_out, int out_size, void* d_ws, size_t ws_size,
                              hipStream_t stream) {
    const float* x     = (const float*)d_in[0];
    const float* W_in  = (const float*)d_in[1];
    const float* b_in  = (const float*)d_in[2];
    const float* W_hid = (const float*)d_in[3];
    const float* b_hid = (const float*)d_in[4];
    const float* W_out = (const float*)d_in[5];
    const float* b_out = (const float*)d_in[6];
    float* out = (float*)d_out;

    int n = in_sizes[0] / 32;              // 1<<20 points
    int nblocks = n / 2048;                // 8 waves * 256 points per block = 512 blocks

    if (ws_size >= (size_t)IMG_BYTES) {
        hipLaunchKernelGGL(prep_kernel, dim3(NWFRAG + 1), dim3(64), 0, stream,
                           W_in, b_in, W_hid, b_hid, W_out, b_out, (uint4*)d_ws);
        hipLaunchKernelGGL((mlp_kernel<true>), dim3(nblocks), dim3(512), 0, stream,
                           x, (const uint4*)d_ws,
                           W_in, b_in, W_hid, b_hid, W_out, b_out, out);
    } else {
        hipLaunchKernelGGL((mlp_kernel<false>), dim3(nblocks), dim3(512), 0, stream,
                           x, (const uint4*)d_ws,
                           W_in, b_in, W_hid, b_hid, W_out, b_out, out);
    }
}

// Round 15
// 45.880 us; speedup vs baseline: 1.2484x; 1.0069x over previous
//
#include <hip/hip_runtime.h>
#include <hip/hip_bf16.h>

// Fully fused MLP: 32 -> 64 -> (4x) 64 -> 3, relu hidden, sigmoid out.
// bf16 MFMA (16x16x32), fp32 accum, operand-swapped (D[neuron][point] = W*H).
// Point index is lane-invariant across layers; neuron relabeling pi baked into
// next-layer weight columns at prep time -> lane-local layer handoff.
//
// Round-15: RESTORE of the proven r13 kernel (46.2us). r14's tile-level
// software pipeline (sequentially-equivalent reorder with ping-pong acc
// buffers) produced finite-wrong output -- second miscompile-class failure in
// this territory (r10/r11 NaN was the first). Ping-pong MFMA accumulators with
// interleaved inline-asm consumers are not trustworthy on this toolchain;
// pipeline line closed. Ledger: staging (99->69), operand-swap (->57),
// setprio+pkrelu (->46.1); all other levers tested-null or entangled.
// This structure's practical plateau: ~2.1x the 19.7us matrix-pipe floor.
//
// Frag map (weights): 0..3 W_in[nt] | 4..35 W_hid[L][nt][f] | 36..37 W_out[f]
// Bias floats at BIAS_F32: [0..63] b_in | [64..319] b_hid | [320..335] b_out+pad

typedef __attribute__((ext_vector_type(8))) short bf16x8;
typedef __attribute__((ext_vector_type(4))) float f32x4;

#define NWFRAG 38
#define BIAS_F32 9728                 // float offset of bias region (= 38*1024/4)
#define IMG_BYTES 40256               // 38912 weight bytes + 336*4 bias bytes
#define IMG_U4 2516

struct F3 { float a, b, c; };         // 12B packed output store

// packed f32x2 -> bf16x2, RNE, 1 instruction. lo = low 16 bits.
__device__ __forceinline__ unsigned cvtpk(float lo, float hi) {
    unsigned r;
    asm("v_cvt_pk_bf16_f32 %0, %1, %2" : "=v"(r) : "v"(lo), "v"(hi));
    return r;
}

// packed bf16x2 relu: int16 max vs register-zero (bit-exact, r9-proven).
__device__ __forceinline__ unsigned pkrelu(unsigned u, unsigned z) {
    unsigned r;
    asm("v_pk_max_i16 %0, %1, %2" : "=v"(r) : "v"(u), "v"(z));
    return r;
}

// inverse of the neuron relabeling pi: k-slot s -> actual neuron index
__device__ __forceinline__ int pinv(int s) {
    return ((s >> 5) & 1) * 32 + ((s >> 2) & 1) * 16 + ((s >> 3) & 3) * 4 + (s & 3);
}

// weight frag value (frag F < 38, lane)
__device__ uint4 frag_value_w(int F, int lane,
        const float* __restrict__ W_in, const float* __restrict__ W_hid,
        const float* __restrict__ W_out) {
    const int j = lane & 15, g = lane >> 4;
    uint4 r = {0u, 0u, 0u, 0u};
    if (F < 4) {                                   // W_in A-frag, natural k
        const float* row = W_in + (F * 16 + j) * 32 + 8 * g;
        r.x = cvtpk(row[0], row[1]); r.y = cvtpk(row[2], row[3]);
        r.z = cvtpk(row[4], row[5]); r.w = cvtpk(row[6], row[7]);
    } else if (F < 36) {                           // W_hid A-frag, pi-relabeled k
        int q = F - 4, L = q >> 3, nt = (q >> 1) & 3, f = q & 1;
        const float* row = W_hid + (L * 64 + nt * 16 + j) * 64;
        int s0 = 32 * f + 8 * g;
        r.x = cvtpk(row[pinv(s0 + 0)], row[pinv(s0 + 1)]);
        r.y = cvtpk(row[pinv(s0 + 2)], row[pinv(s0 + 3)]);
        r.z = cvtpk(row[pinv(s0 + 4)], row[pinv(s0 + 5)]);
        r.w = cvtpk(row[pinv(s0 + 6)], row[pinv(s0 + 7)]);
    } else {                                       // W_out A-frag (rows 3..15 zero)
        int f = F - 36;
        if (j < 3) {
            const float* row = W_out + j * 64;
            int s0 = 32 * f + 8 * g;
            r.x = cvtpk(row[pinv(s0 + 0)], row[pinv(s0 + 1)]);
            r.y = cvtpk(row[pinv(s0 + 2)], row[pinv(s0 + 3)]);
            r.z = cvtpk(row[pinv(s0 + 4)], row[pinv(s0 + 5)]);
            r.w = cvtpk(row[pinv(s0 + 6)], row[pinv(s0 + 7)]);
        }
    }
    return r;
}

__device__ __forceinline__ float bias_val(int idx,
        const float* __restrict__ b_in, const float* __restrict__ b_hid,
        const float* __restrict__ b_out) {
    if (idx < 64)  return b_in[idx];
    if (idx < 320) return b_hid[idx - 64];
    return (idx - 320 < 3) ? b_out[idx - 320] : 0.f;
}

__global__ void prep_kernel(const float* __restrict__ W_in,  const float* __restrict__ b_in,
                            const float* __restrict__ W_hid, const float* __restrict__ b_hid,
                            const float* __restrict__ W_out, const float* __restrict__ b_out,
                            uint4* __restrict__ img) {
    const int F = blockIdx.x, t = threadIdx.x;
    if (F < NWFRAG) {
        img[F * 64 + t] = frag_value_w(F, t, W_in, W_hid, W_out);
    } else {
        float* fb = (float*)img + BIAS_F32;
        for (int idx = t; idx < 336; idx += 64)
            fb[idx] = bias_val(idx, b_in, b_hid, b_out);
    }
}

// relu + lane-local pi-pack: acc[4] (f32x4) -> h[2] (bf16x8)
// cvtpk first, then packed int16 relu (bit-exact vs fmaxf-then-cvtpk).
__device__ __forceinline__ void relu_pack(const f32x4 a[4], bf16x8 h[2], unsigned z) {
#pragma unroll
    for (int f = 0; f < 2; ++f) {
        union { bf16x8 v; unsigned u[4]; } t;
        t.u[0] = pkrelu(cvtpk(a[2 * f][0], a[2 * f][1]), z);
        t.u[1] = pkrelu(cvtpk(a[2 * f][2], a[2 * f][3]), z);
        t.u[2] = pkrelu(cvtpk(a[2 * f + 1][0], a[2 * f + 1][1]), z);
        t.u[3] = pkrelu(cvtpk(a[2 * f + 1][2], a[2 * f + 1][3]), z);
        h[f] = t.v;
    }
}

#define MFMA(a, b, c) __builtin_amdgcn_mfma_f32_16x16x32_bf16((a), (b), (c), 0, 0, 0)

template<bool FAST>
__global__ __launch_bounds__(512, 4) void mlp_kernel(
        const float* __restrict__ x, const uint4* __restrict__ img,
        const float* __restrict__ gW_in,  const float* __restrict__ gb_in,
        const float* __restrict__ gW_hid, const float* __restrict__ gb_hid,
        const float* __restrict__ gW_out, const float* __restrict__ gb_out,
        float* __restrict__ out) {
    __shared__ uint4 simg[IMG_U4];
    const int tid = threadIdx.x;

    if (FAST) {
#pragma unroll
        for (int i = 0; i < 5; ++i) {
            int idx = tid + i * 512;
            if (idx < IMG_U4) simg[idx] = img[idx];
        }
    } else {
        for (int idx = tid; idx < NWFRAG * 64; idx += 512)
            simg[idx] = frag_value_w(idx >> 6, idx & 63, gW_in, gW_hid, gW_out);
        {
            float* fb = (float*)simg + BIAS_F32;
            for (int idx = tid; idx < 336; idx += 512)
                fb[idx] = bias_val(idx, gb_in, gb_hid, gb_out);
        }
    }

    const int wave = tid >> 6, lane = tid & 63;
    const int j = lane & 15, g = lane >> 4;
    const int base = (blockIdx.x * 8 + wave) * 256;

    // iter-0 x load issued before the barrier (hides under staging)
    f32x4 raw[4][2];
    {
        const float* xp = x + (size_t)(base + j) * 32 + 8 * g;
#pragma unroll
        for (int t = 0; t < 4; ++t) {
            raw[t][0] = *(const f32x4*)(xp + t * 512);
            raw[t][1] = *(const f32x4*)(xp + t * 512 + 4);
        }
    }
    __syncthreads();

    const uint4*  lp = &simg[lane];              // weight frag F at lp[F*64]
    const float*  sb = (const float*)simg + BIAS_F32;
    const unsigned z = 0;                        // register zero for pkrelu

#pragma unroll 1
    for (int it = 0; it < 4; ++it) {
        const int p0 = base + it * 64;

        // pack current x into B-frags (raw regs die here)
        bf16x8 xf[4];
#pragma unroll
        for (int t = 0; t < 4; ++t) {
            union { bf16x8 v; unsigned u[4]; } a;
            a.u[0] = cvtpk(raw[t][0][0], raw[t][0][1]);
            a.u[1] = cvtpk(raw[t][0][2], raw[t][0][3]);
            a.u[2] = cvtpk(raw[t][1][0], raw[t][1][1]);
            a.u[3] = cvtpk(raw[t][1][2], raw[t][1][3]);
            xf[t] = a.v;
        }

        // ======== input layer: all 4 tiles ========
        bf16x8 hfrag[4][2];
        {
            f32x4 acc[4][4];
            __builtin_amdgcn_s_setprio(3);
#pragma unroll
            for (int nt = 0; nt < 4; ++nt) {
                bf16x8 w  = *(const bf16x8*)&lp[nt * 64];
                f32x4  bz = *(const f32x4*)&sb[nt * 16 + 4 * g];
#pragma unroll
                for (int t = 0; t < 4; ++t)
                    acc[t][nt] = MFMA(w, xf[t], bz);
            }
            __builtin_amdgcn_s_setprio(0);
#pragma unroll
            for (int t = 0; t < 4; ++t) relu_pack(acc[t], hfrag[t], z);
        }

        // ======== 4 hidden layers: weights read once, tiles pair-staged ========
#pragma unroll
        for (int L = 0; L < 4; ++L) {
            const int wb = (4 + L * 8) * 64;
            bf16x8 w0[4], w1[4]; f32x4 bz[4];
#pragma unroll
            for (int nt = 0; nt < 4; ++nt) {
                w0[nt] = *(const bf16x8*)&lp[wb + (2 * nt) * 64];
                w1[nt] = *(const bf16x8*)&lp[wb + (2 * nt + 1) * 64];
                bz[nt] = *(const f32x4*)&sb[64 + L * 64 + nt * 16 + 4 * g];
            }
#pragma unroll
            for (int pr = 0; pr < 2; ++pr) {
                f32x4 pa[2][4];
                __builtin_amdgcn_s_setprio(3);
#pragma unroll
                for (int q = 0; q < 2; ++q)
#pragma unroll
                    for (int nt = 0; nt < 4; ++nt)
                        pa[q][nt] = MFMA(w0[nt], hfrag[2 * pr + q][0], bz[nt]);
#pragma unroll
                for (int q = 0; q < 2; ++q)
#pragma unroll
                    for (int nt = 0; nt < 4; ++nt)
                        pa[q][nt] = MFMA(w1[nt], hfrag[2 * pr + q][1], pa[q][nt]);
                __builtin_amdgcn_s_setprio(0);
#pragma unroll
                for (int q = 0; q < 2; ++q) relu_pack(pa[q], hfrag[2 * pr + q], z);
            }
        }

        // ======== output layer ========
        bf16x8 wo0 = *(const bf16x8*)&lp[36 * 64];
        bf16x8 wo1 = *(const bf16x8*)&lp[37 * 64];
        f32x4  bo  = *(const f32x4*)&sb[320 + 4 * g];   // g>0 rows read zero pad
        f32x4 zacc[4];
        __builtin_amdgcn_s_setprio(3);
#pragma unroll
        for (int t = 0; t < 4; ++t) {
            f32x4 tmp = MFMA(wo0, hfrag[t][0], bo);
            zacc[t] = MFMA(wo1, hfrag[t][1], tmp);
        }
        __builtin_amdgcn_s_setprio(0);

        // prefetch next iter's x (raw regs were dead since pack)
        {
            const int pn = (it < 3) ? p0 + 64 : p0;
            const float* xp = x + (size_t)(pn + j) * 32 + 8 * g;
#pragma unroll
            for (int t = 0; t < 4; ++t) {
                raw[t][0] = *(const f32x4*)(xp + t * 512);
                raw[t][1] = *(const f32x4*)(xp + t * 512 + 4);
            }
        }

        // sigmoid + packed 12B stores (rows 0..2 live in g==0)
        if (g == 0) {
            float* ob = out + (size_t)(p0 + j) * 3;
#pragma unroll
            for (int t = 0; t < 4; ++t) {
                F3 v;
                v.a = __builtin_amdgcn_rcpf(1.f + __expf(-zacc[t][0]));
                v.b = __builtin_amdgcn_rcpf(1.f + __expf(-zacc[t][1]));
                v.c = __builtin_amdgcn_rcpf(1.f + __expf(-zacc[t][2]));
                *(F3*)(ob + t * 48) = v;
            }
        }
    }
}

extern "C" void kernel_launch(void* const* d_in, const int* in_sizes, int n_in,
                              void* d_out, int out_size, void* d_ws, size_t ws_size,
                              hipStream_t stream) {
    const float* x     = (const float*)d_in[0];
    const float* W_in  = (const float*)d_in[1];
    const float* b_in  = (const float*)d_in[2];
    const float* W_hid = (const float*)d_in[3];
    const float* b_hid = (const float*)d_in[4];
    const float* W_out = (const float*)d_in[5];
    const float* b_out = (const float*)d_in[6];
    float* out = (float*)d_out;

    int n = in_sizes[0] / 32;              // 1<<20 points
    int nblocks = n / 2048;                // 8 waves * 256 points per block = 512 blocks

    if (ws_size >= (size_t)IMG_BYTES) {
        hipLaunchKernelGGL(prep_kernel, dim3(NWFRAG + 1), dim3(64), 0, stream,
                           W_in, b_in, W_hid, b_hid, W_out, b_out, (uint4*)d_ws);
        hipLaunchKernelGGL((mlp_kernel<true>), dim3(nblocks), dim3(512), 0, stream,
                           x, (const uint4*)d_ws,
                           W_in, b_in, W_hid, b_hid, W_out, b_out, out);
    } else {
        hipLaunchKernelGGL((mlp_kernel<false>), dim3(nblocks), dim3(512), 0, stream,
                           x, (const uint4*)d_ws,
                           W_in, b_in, W_hid, b_hid, W_out, b_out, out);
    }
}

// Round 17
// 45.778 us; speedup vs baseline: 1.2512x; 1.0022x over previous
//
#include <hip/hip_runtime.h>
#include <hip/hip_bf16.h>

// Fully fused MLP: 32 -> 64 -> (4x) 64 -> 3, relu hidden, sigmoid out.
// bf16 MFMA (16x16x32), fp32 accum, operand-swapped (D[neuron][point] = W*H).
// Point index is lane-invariant across layers; neuron relabeling pi baked into
// next-layer weight columns at prep time -> lane-local layer handoff.
//
// Round-17: FINAL RESTORE of the proven optimum (r13/r15, 45.9-46.2us).
// r16 proved the per-cluster setprio fences are CORRECTNESS-load-bearing:
// widening the prio regions (letting the scheduler interleave inline-asm
// relu/cvtpk with in-flight MFMA chains) corrupts results -- same failure
// class as r14's hand interleave and r10/r11's NaN. The ~26us gap to the
// 19.7us matrix-pipe floor requires exactly that interleave -> unreachable
// at HIP source level on this toolchain. Ledger: staging 99->69, operand-swap
// ->57, setprio+pkrelu ->46.1; LDS-traffic x2 null, VALU trims null,
// de-convoy null, prio3 null, 32x32 -24%, TLP capped at 4 waves/SIMD,
// fp8 precision-barred. ~852 TF effective (~34% dense bf16 peak).
//
// Frag map (weights): 0..3 W_in[nt] | 4..35 W_hid[L][nt][f] | 36..37 W_out[f]
// Bias floats at BIAS_F32: [0..63] b_in | [64..319] b_hid | [320..335] b_out+pad

typedef __attribute__((ext_vector_type(8))) short bf16x8;
typedef __attribute__((ext_vector_type(4))) float f32x4;

#define NWFRAG 38
#define BIAS_F32 9728                 // float offset of bias region (= 38*1024/4)
#define IMG_BYTES 40256               // 38912 weight bytes + 336*4 bias bytes
#define IMG_U4 2516

struct F3 { float a, b, c; };         // 12B packed output store

// packed f32x2 -> bf16x2, RNE, 1 instruction. lo = low 16 bits.
__device__ __forceinline__ unsigned cvtpk(float lo, float hi) {
    unsigned r;
    asm("v_cvt_pk_bf16_f32 %0, %1, %2" : "=v"(r) : "v"(lo), "v"(hi));
    return r;
}

// packed bf16x2 relu: int16 max vs register-zero (bit-exact, r9-proven).
__device__ __forceinline__ unsigned pkrelu(unsigned u, unsigned z) {
    unsigned r;
    asm("v_pk_max_i16 %0, %1, %2" : "=v"(r) : "v"(u), "v"(z));
    return r;
}

// inverse of the neuron relabeling pi: k-slot s -> actual neuron index
__device__ __forceinline__ int pinv(int s) {
    return ((s >> 5) & 1) * 32 + ((s >> 2) & 1) * 16 + ((s >> 3) & 3) * 4 + (s & 3);
}

// weight frag value (frag F < 38, lane)
__device__ uint4 frag_value_w(int F, int lane,
        const float* __restrict__ W_in, const float* __restrict__ W_hid,
        const float* __restrict__ W_out) {
    const int j = lane & 15, g = lane >> 4;
    uint4 r = {0u, 0u, 0u, 0u};
    if (F < 4) {                                   // W_in A-frag, natural k
        const float* row = W_in + (F * 16 + j) * 32 + 8 * g;
        r.x = cvtpk(row[0], row[1]); r.y = cvtpk(row[2], row[3]);
        r.z = cvtpk(row[4], row[5]); r.w = cvtpk(row[6], row[7]);
    } else if (F < 36) {                           // W_hid A-frag, pi-relabeled k
        int q = F - 4, L = q >> 3, nt = (q >> 1) & 3, f = q & 1;
        const float* row = W_hid + (L * 64 + nt * 16 + j) * 64;
        int s0 = 32 * f + 8 * g;
        r.x = cvtpk(row[pinv(s0 + 0)], row[pinv(s0 + 1)]);
        r.y = cvtpk(row[pinv(s0 + 2)], row[pinv(s0 + 3)]);
        r.z = cvtpk(row[pinv(s0 + 4)], row[pinv(s0 + 5)]);
        r.w = cvtpk(row[pinv(s0 + 6)], row[pinv(s0 + 7)]);
    } else {                                       // W_out A-frag (rows 3..15 zero)
        int f = F - 36;
        if (j < 3) {
            const float* row = W_out + j * 64;
            int s0 = 32 * f + 8 * g;
            r.x = cvtpk(row[pinv(s0 + 0)], row[pinv(s0 + 1)]);
            r.y = cvtpk(row[pinv(s0 + 2)], row[pinv(s0 + 3)]);
            r.z = cvtpk(row[pinv(s0 + 4)], row[pinv(s0 + 5)]);
            r.w = cvtpk(row[pinv(s0 + 6)], row[pinv(s0 + 7)]);
        }
    }
    return r;
}

__device__ __forceinline__ float bias_val(int idx,
        const float* __restrict__ b_in, const float* __restrict__ b_hid,
        const float* __restrict__ b_out) {
    if (idx < 64)  return b_in[idx];
    if (idx < 320) return b_hid[idx - 64];
    return (idx - 320 < 3) ? b_out[idx - 320] : 0.f;
}

__global__ void prep_kernel(const float* __restrict__ W_in,  const float* __restrict__ b_in,
                            const float* __restrict__ W_hid, const float* __restrict__ b_hid,
                            const float* __restrict__ W_out, const float* __restrict__ b_out,
                            uint4* __restrict__ img) {
    const int F = blockIdx.x, t = threadIdx.x;
    if (F < NWFRAG) {
        img[F * 64 + t] = frag_value_w(F, t, W_in, W_hid, W_out);
    } else {
        float* fb = (float*)img + BIAS_F32;
        for (int idx = t; idx < 336; idx += 64)
            fb[idx] = bias_val(idx, b_in, b_hid, b_out);
    }
}

// relu + lane-local pi-pack: acc[4] (f32x4) -> h[2] (bf16x8)
// cvtpk first, then packed int16 relu (bit-exact vs fmaxf-then-cvtpk).
__device__ __forceinline__ void relu_pack(const f32x4 a[4], bf16x8 h[2], unsigned z) {
#pragma unroll
    for (int f = 0; f < 2; ++f) {
        union { bf16x8 v; unsigned u[4]; } t;
        t.u[0] = pkrelu(cvtpk(a[2 * f][0], a[2 * f][1]), z);
        t.u[1] = pkrelu(cvtpk(a[2 * f][2], a[2 * f][3]), z);
        t.u[2] = pkrelu(cvtpk(a[2 * f + 1][0], a[2 * f + 1][1]), z);
        t.u[3] = pkrelu(cvtpk(a[2 * f + 1][2], a[2 * f + 1][3]), z);
        h[f] = t.v;
    }
}

#define MFMA(a, b, c) __builtin_amdgcn_mfma_f32_16x16x32_bf16((a), (b), (c), 0, 0, 0)

template<bool FAST>
__global__ __launch_bounds__(512, 4) void mlp_kernel(
        const float* __restrict__ x, const uint4* __restrict__ img,
        const float* __restrict__ gW_in,  const float* __restrict__ gb_in,
        const float* __restrict__ gW_hid, const float* __restrict__ gb_hid,
        const float* __restrict__ gW_out, const float* __restrict__ gb_out,
        float* __restrict__ out) {
    __shared__ uint4 simg[IMG_U4];
    const int tid = threadIdx.x;

    if (FAST) {
#pragma unroll
        for (int i = 0; i < 5; ++i) {
            int idx = tid + i * 512;
            if (idx < IMG_U4) simg[idx] = img[idx];
        }
    } else {
        for (int idx = tid; idx < NWFRAG * 64; idx += 512)
            simg[idx] = frag_value_w(idx >> 6, idx & 63, gW_in, gW_hid, gW_out);
        {
            float* fb = (float*)simg + BIAS_F32;
            for (int idx = tid; idx < 336; idx += 512)
                fb[idx] = bias_val(idx, gb_in, gb_hid, gb_out);
        }
    }

    const int wave = tid >> 6, lane = tid & 63;
    const int j = lane & 15, g = lane >> 4;
    const int base = (blockIdx.x * 8 + wave) * 256;

    // iter-0 x load issued before the barrier (hides under staging)
    f32x4 raw[4][2];
    {
        const float* xp = x + (size_t)(base + j) * 32 + 8 * g;
#pragma unroll
        for (int t = 0; t < 4; ++t) {
            raw[t][0] = *(const f32x4*)(xp + t * 512);
            raw[t][1] = *(const f32x4*)(xp + t * 512 + 4);
        }
    }
    __syncthreads();

    const uint4*  lp = &simg[lane];              // weight frag F at lp[F*64]
    const float*  sb = (const float*)simg + BIAS_F32;
    const unsigned z = 0;                        // register zero for pkrelu

#pragma unroll 1
    for (int it = 0; it < 4; ++it) {
        const int p0 = base + it * 64;

        // pack current x into B-frags (raw regs die here)
        bf16x8 xf[4];
#pragma unroll
        for (int t = 0; t < 4; ++t) {
            union { bf16x8 v; unsigned u[4]; } a;
            a.u[0] = cvtpk(raw[t][0][0], raw[t][0][1]);
            a.u[1] = cvtpk(raw[t][0][2], raw[t][0][3]);
            a.u[2] = cvtpk(raw[t][1][0], raw[t][1][1]);
            a.u[3] = cvtpk(raw[t][1][2], raw[t][1][3]);
            xf[t] = a.v;
        }

        // ======== input layer: all 4 tiles ========
        bf16x8 hfrag[4][2];
        {
            f32x4 acc[4][4];
            __builtin_amdgcn_s_setprio(3);
#pragma unroll
            for (int nt = 0; nt < 4; ++nt) {
                bf16x8 w  = *(const bf16x8*)&lp[nt * 64];
                f32x4  bz = *(const f32x4*)&sb[nt * 16 + 4 * g];
#pragma unroll
                for (int t = 0; t < 4; ++t)
                    acc[t][nt] = MFMA(w, xf[t], bz);
            }
            __builtin_amdgcn_s_setprio(0);
#pragma unroll
            for (int t = 0; t < 4; ++t) relu_pack(acc[t], hfrag[t], z);
        }

        // ======== 4 hidden layers: weights read once, tiles pair-staged ========
#pragma unroll
        for (int L = 0; L < 4; ++L) {
            const int wb = (4 + L * 8) * 64;
            bf16x8 w0[4], w1[4]; f32x4 bz[4];
#pragma unroll
            for (int nt = 0; nt < 4; ++nt) {
                w0[nt] = *(const bf16x8*)&lp[wb + (2 * nt) * 64];
                w1[nt] = *(const bf16x8*)&lp[wb + (2 * nt + 1) * 64];
                bz[nt] = *(const f32x4*)&sb[64 + L * 64 + nt * 16 + 4 * g];
            }
#pragma unroll
            for (int pr = 0; pr < 2; ++pr) {
                f32x4 pa[2][4];
                __builtin_amdgcn_s_setprio(3);
#pragma unroll
                for (int q = 0; q < 2; ++q)
#pragma unroll
                    for (int nt = 0; nt < 4; ++nt)
                        pa[q][nt] = MFMA(w0[nt], hfrag[2 * pr + q][0], bz[nt]);
#pragma unroll
                for (int q = 0; q < 2; ++q)
#pragma unroll
                    for (int nt = 0; nt < 4; ++nt)
                        pa[q][nt] = MFMA(w1[nt], hfrag[2 * pr + q][1], pa[q][nt]);
                __builtin_amdgcn_s_setprio(0);
#pragma unroll
                for (int q = 0; q < 2; ++q) relu_pack(pa[q], hfrag[2 * pr + q], z);
            }
        }

        // ======== output layer ========
        bf16x8 wo0 = *(const bf16x8*)&lp[36 * 64];
        bf16x8 wo1 = *(const bf16x8*)&lp[37 * 64];
        f32x4  bo  = *(const f32x4*)&sb[320 + 4 * g];   // g>0 rows read zero pad
        f32x4 zacc[4];
        __builtin_amdgcn_s_setprio(3);
#pragma unroll
        for (int t = 0; t < 4; ++t) {
            f32x4 tmp = MFMA(wo0, hfrag[t][0], bo);
            zacc[t] = MFMA(wo1, hfrag[t][1], tmp);
        }
        __builtin_amdgcn_s_setprio(0);

        // prefetch next iter's x (raw regs were dead since pack)
        {
            const int pn = (it < 3) ? p0 + 64 : p0;
            const float* xp = x + (size_t)(pn + j) * 32 + 8 * g;
#pragma unroll
            for (int t = 0; t < 4; ++t) {
                raw[t][0] = *(const f32x4*)(xp + t * 512);
                raw[t][1] = *(const f32x4*)(xp + t * 512 + 4);
            }
        }

        // sigmoid + packed 12B stores (rows 0..2 live in g==0)
        if (g == 0) {
            float* ob = out + (size_t)(p0 + j) * 3;
#pragma unroll
            for (int t = 0; t < 4; ++t) {
                F3 v;
                v.a = __builtin_amdgcn_rcpf(1.f + __expf(-zacc[t][0]));
                v.b = __builtin_amdgcn_rcpf(1.f + __expf(-zacc[t][1]));
                v.c = __builtin_amdgcn_rcpf(1.f + __expf(-zacc[t][2]));
                *(F3*)(ob + t * 48) = v;
            }
        }
    }
}

extern "C" void kernel_launch(void* const* d_in, const int* in_sizes, int n_in,
                              void* d_out, int out_size, void* d_ws, size_t ws_size,
                              hipStream_t stream) {
    const float* x     = (const float*)d_in[0];
    const float* W_in  = (const float*)d_in[1];
    const float* b_in  = (const float*)d_in[2];
    const float* W_hid = (const float*)d_in[3];
    const float* b_hid = (const float*)d_in[4];
    const float* W_out = (const float*)d_in[5];
    const float* b_out = (const float*)d_in[6];
    float* out = (float*)d_out;

    int n = in_sizes[0] / 32;              // 1<<20 points
    int nblocks = n / 2048;                // 8 waves * 256 points per block = 512 blocks

    if (ws_size >= (size_t)IMG_BYTES) {
        hipLaunchKernelGGL(prep_kernel, dim3(NWFRAG + 1), dim3(64), 0, stream,
                           W_in, b_in, W_hid, b_hid, W_out, b_out, (uint4*)d_ws);
        hipLaunchKernelGGL((mlp_kernel<true>), dim3(nblocks), dim3(512), 0, stream,
                           x, (const uint4*)d_ws,
                           W_in, b_in, W_hid, b_hid, W_out, b_out, out);
    } else {
        hipLaunchKernelGGL((mlp_kernel<false>), dim3(nblocks), dim3(512), 0, stream,
                           x, (const uint4*)d_ws,
                           W_in, b_in, W_hid, b_hid, W_out, b_out, out);
    }
}